// Round 2
// baseline (1639.552 us; speedup 1.0000x reference)
//
#include <hip/hip_runtime.h>
#include <hip/hip_bf16.h>

#define N_NODES   50000
#define N_EDGES   800000
#define NF        32
#define DE        64
#define NH        8
#define CT        512     // NH*DE
#define DMLP      512
#define NG        2000
#define NEGS      0.2f

// ---------------- CSR build (shared by both GAT layers) ----------------

__global__ void init_count_k(int* __restrict__ cnt) {
    int i = blockIdx.x * 256 + threadIdx.x;
    if (i < N_NODES) cnt[i] = 1;   // start at 1: the self-loop
}

__global__ void hist_k(const int* __restrict__ ei, int* __restrict__ cnt) {
    int e = blockIdx.x * 256 + threadIdx.x;
    if (e < N_EDGES) atomicAdd(&cnt[ei[N_EDGES + e]], 1);   // row 1 = dst
}

// single-block exclusive scan over 50000 counts
__global__ void scan_k(const int* __restrict__ cnt, int* __restrict__ off) {
    __shared__ int buf[1024];
    __shared__ int carry;
    int tid = threadIdx.x;
    if (tid == 0) carry = 0;
    __syncthreads();
    for (int base = 0; base < N_NODES; base += 1024) {
        int v = (base + tid < N_NODES) ? cnt[base + tid] : 0;
        buf[tid] = v;
        __syncthreads();
        for (int d = 1; d < 1024; d <<= 1) {
            int t = (tid >= d) ? buf[tid - d] : 0;
            __syncthreads();
            buf[tid] += t;
            __syncthreads();
        }
        int incl = buf[tid];
        int c = carry;
        int tot = buf[1023];
        __syncthreads();
        if (base + tid < N_NODES) off[base + tid] = c + incl - v;
        if (tid == 0) carry = c + tot;
        __syncthreads();
    }
    if (tid == 0) off[N_NODES] = carry;
}

__global__ void scatter_k(const int* __restrict__ ei, const int* __restrict__ off,
                          int* __restrict__ cur, int* __restrict__ ssrc) {
    int e = blockIdx.x * 256 + threadIdx.x;
    if (e < N_EDGES) {
        int s = ei[e];
        int d = ei[N_EDGES + e];
        int p = off[d] + atomicAdd(&cur[d], 1);
        ssrc[p] = s;
    } else if (e < N_EDGES + N_NODES) {
        int i = e - N_EDGES;                    // self loop
        int p = off[i] + atomicAdd(&cur[i], 1);
        ssrc[p] = i;
    }
}

// ---------------- dense GEMM: Y[nrows,512] = X[nrows,K] @ W[K,512] ----------------
// 16 rows per block, 256 threads, thread owns channels (tid, tid+256).
// Nontemporal stores keep the streamed output out of L2 so W stays cached.

template<int K, bool RELU_BIAS>
__global__ void gemm_k(const float* __restrict__ X, const float* __restrict__ W,
                       const float* __restrict__ bias, float* __restrict__ Y, int nrows) {
    __shared__ float xs[16][K];
    int tid = threadIdx.x;
    int row0 = blockIdx.x * 16;
    for (int idx = tid; idx < 16 * K; idx += 256) {
        int r = idx / K, k = idx - r * K;
        int row = row0 + r;
        xs[r][k] = (row < nrows) ? X[(size_t)row * K + k] : 0.f;
    }
    __syncthreads();
    float acc0[16], acc1[16];
    #pragma unroll
    for (int r = 0; r < 16; ++r) { acc0[r] = 0.f; acc1[r] = 0.f; }
    for (int k = 0; k < K; ++k) {
        float w0 = W[(size_t)k * CT + tid];
        float w1 = W[(size_t)k * CT + tid + 256];
        #pragma unroll
        for (int r = 0; r < 16; ++r) {
            acc0[r] = fmaf(xs[r][k], w0, acc0[r]);
            acc1[r] = fmaf(xs[r][k], w1, acc1[r]);
        }
    }
    float b0 = 0.f, b1 = 0.f;
    if (RELU_BIAS) { b0 = bias[tid]; b1 = bias[tid + 256]; }
    #pragma unroll
    for (int r = 0; r < 16; ++r) {
        int row = row0 + r;
        if (row < nrows) {
            float v0 = acc0[r], v1 = acc1[r];
            if (RELU_BIAS) { v0 = fmaxf(v0 + b0, 0.f); v1 = fmaxf(v1 + b1, 0.f); }
            __builtin_nontemporal_store(v0, &Y[(size_t)row * CT + tid]);
            __builtin_nontemporal_store(v1, &Y[(size_t)row * CT + tid + 256]);
        }
    }
}

// ---------------- per-(node,head) attention logits ----------------

__global__ void alpha_k(const float* __restrict__ h, const float* __restrict__ a_src,
                        const float* __restrict__ a_dst, float* __restrict__ as_,
                        float* __restrict__ ad_) {
    __shared__ float sa[CT], sd[CT];
    int tid = threadIdx.x;
    for (int i = tid; i < CT; i += 256) { sa[i] = a_src[i]; sd[i] = a_dst[i]; }
    __syncthreads();
    int gidx = blockIdx.x * 256 + tid;
    if (gidx >= N_NODES * NH) return;
    int n = gidx >> 3, hd = gidx & 7;
    const float4* hp = (const float4*)(h + (size_t)n * CT + hd * DE);
    float s1 = 0.f, s2 = 0.f;
    #pragma unroll
    for (int q = 0; q < DE / 4; ++q) {
        float4 v = hp[q];
        int b = hd * DE + q * 4;
        s1 += v.x * sa[b] + v.y * sa[b + 1] + v.z * sa[b + 2] + v.w * sa[b + 3];
        s2 += v.x * sd[b] + v.y * sd[b + 1] + v.z * sd[b + 2] + v.w * sd[b + 3];
    }
    as_[gidx] = s1;
    ad_[gidx] = s2;
}

// ---------------- GAT aggregation: one node per WAVE, no LDS, no barriers ----------------
// lane owns channels [lane*8, lane*8+8) (head = lane>>3).
// Phase A: 8 lanes/head online softmax stats over edges, shfl-reduce 1/2/4.
// Phase B: scalar-uniform edge walk, 2x float4 gather per lane, unroll x2.
// CONCAT=false: head-mean via shfl 8/16/32, lanes 0-7 store 64 channels.
// CONCAT=true : fused graph pooling, 8 scalar atomicAdds per lane.

__device__ inline float4 fma4(float a, float4 v, float4 c) {
    c.x = fmaf(a, v.x, c.x); c.y = fmaf(a, v.y, c.y);
    c.z = fmaf(a, v.z, c.z); c.w = fmaf(a, v.w, c.w);
    return c;
}

__device__ inline float4 add4(float4 a, float4 b) {
    a.x += b.x; a.y += b.y; a.z += b.z; a.w += b.w; return a;
}

__device__ inline float4 shfl_xor4(float4 v, int m) {
    float4 r;
    r.x = __shfl_xor(v.x, m, 64); r.y = __shfl_xor(v.y, m, 64);
    r.z = __shfl_xor(v.z, m, 64); r.w = __shfl_xor(v.w, m, 64);
    return r;
}

template<bool CONCAT>
__global__ __launch_bounds__(256) void agg_wave_k(
        const float* __restrict__ h, const float* __restrict__ as_,
        const float* __restrict__ ad_, const int* __restrict__ ssrc,
        const int* __restrict__ off, const float* __restrict__ bias,
        float* __restrict__ out, const int* __restrict__ batch,
        float* __restrict__ g) {
    int wv = __builtin_amdgcn_readfirstlane(blockIdx.x * 4 + (threadIdx.x >> 6));
    if (wv >= N_NODES) return;
    int lane = threadIdx.x & 63;
    int hd = lane >> 3;

    int beg = off[wv], end = off[wv + 1];        // scalar loads (wv in SGPR)
    float adv = ad_[(size_t)wv * NH + hd];

    // Phase A: per-head online (max, sum); 8 lanes per head, stride 8
    float m = -1e30f, s = 0.f;
    for (int j = beg + (lane & 7); j < end; j += 8) {
        int sj = ssrc[j];
        float e = as_[(size_t)sj * NH + hd] + adv;
        e = e > 0.f ? e : NEGS * e;
        float mo = fmaxf(m, e);
        s = s * __expf(m - mo) + __expf(e - mo);
        m = mo;
    }
    #pragma unroll
    for (int d = 1; d <= 4; d <<= 1) {
        float m2 = __shfl_xor(m, d, 64);
        float s2 = __shfl_xor(s, d, 64);
        float mo = fmaxf(m, m2);
        s = s * __expf(m - mo) + s2 * __expf(m2 - mo);
        m = mo;
    }
    float inv = 1.f / (s + 1e-16f);

    // Phase B: gather-accumulate, edges unrolled x2, wave-uniform src ids
    float4 a0 = {0.f, 0.f, 0.f, 0.f}, a1 = {0.f, 0.f, 0.f, 0.f};
    int j = beg;
    for (; j + 2 <= end; j += 2) {
        int sA = ssrc[j], sB = ssrc[j + 1];
        float eA = as_[(size_t)sA * NH + hd] + adv;
        float eB = as_[(size_t)sB * NH + hd] + adv;
        const float4* pA = (const float4*)(h + (size_t)sA * CT) + lane * 2;
        const float4* pB = (const float4*)(h + (size_t)sB * CT) + lane * 2;
        float4 vA0 = pA[0], vA1 = pA[1];
        float4 vB0 = pB[0], vB1 = pB[1];
        eA = eA > 0.f ? eA : NEGS * eA;
        eB = eB > 0.f ? eB : NEGS * eB;
        float alA = __expf(eA - m) * inv;
        float alB = __expf(eB - m) * inv;
        a0 = fma4(alA, vA0, a0); a1 = fma4(alA, vA1, a1);
        a0 = fma4(alB, vB0, a0); a1 = fma4(alB, vB1, a1);
    }
    if (j < end) {
        int sA = ssrc[j];
        float eA = as_[(size_t)sA * NH + hd] + adv;
        const float4* pA = (const float4*)(h + (size_t)sA * CT) + lane * 2;
        float4 vA0 = pA[0], vA1 = pA[1];
        eA = eA > 0.f ? eA : NEGS * eA;
        float alA = __expf(eA - m) * inv;
        a0 = fma4(alA, vA0, a0); a1 = fma4(alA, vA1, a1);
    }

    if (CONCAT) {
        int b = __builtin_amdgcn_readfirstlane(batch[wv]);
        const float4* bp = (const float4*)(bias + lane * 8);
        float4 bi0 = bp[0], bi1 = bp[1];
        float* gp = g + (size_t)b * CT + lane * 8;
        atomicAdd(gp + 0, a0.x + bi0.x);
        atomicAdd(gp + 1, a0.y + bi0.y);
        atomicAdd(gp + 2, a0.z + bi0.z);
        atomicAdd(gp + 3, a0.w + bi0.w);
        atomicAdd(gp + 4, a1.x + bi1.x);
        atomicAdd(gp + 5, a1.y + bi1.y);
        atomicAdd(gp + 6, a1.z + bi1.z);
        atomicAdd(gp + 7, a1.w + bi1.w);
    } else {
        // mean over heads: sum lanes differing in bits 3..5 (same within-head offset)
        #pragma unroll
        for (int d = 8; d <= 32; d <<= 1) {
            a0 = add4(a0, shfl_xor4(a0, d));
            a1 = add4(a1, shfl_xor4(a1, d));
        }
        if (lane < 8) {
            const float4* bp = (const float4*)(bias + lane * 8);
            float4 bi0 = bp[0], bi1 = bp[1];
            float4 r0, r1;
            const float sc = 1.f / NH;
            r0.x = a0.x * sc + bi0.x; r0.y = a0.y * sc + bi0.y;
            r0.z = a0.z * sc + bi0.z; r0.w = a0.w * sc + bi0.w;
            r1.x = a1.x * sc + bi1.x; r1.y = a1.y * sc + bi1.y;
            r1.z = a1.z * sc + bi1.z; r1.w = a1.w * sc + bi1.w;
            float4* op = (float4*)(out + (size_t)wv * DE + lane * 8);
            op[0] = r0; op[1] = r1;
        }
    }
}

// ---------------- final MLP projection to 1 ----------------

__global__ void mlp_out_k(const float* __restrict__ gin, const float* __restrict__ w,
                          const float* __restrict__ b, float* __restrict__ out) {
    int row = blockIdx.x * 4 + (threadIdx.x >> 6);
    int lane = threadIdx.x & 63;
    if (row >= NG) return;
    float s = 0.f;
    for (int k = lane; k < DMLP; k += 64) s += gin[(size_t)row * DMLP + k] * w[k];
    #pragma unroll
    for (int d = 32; d >= 1; d >>= 1) s += __shfl_xor(s, d, 64);
    if (lane == 0) out[row] = s + b[0];
}

// ---------------- launch ----------------

extern "C" void kernel_launch(void* const* d_in, const int* in_sizes, int n_in,
                              void* d_out, int out_size, void* d_ws, size_t ws_size,
                              hipStream_t stream) {
    const float* x     = (const float*)d_in[0];
    const int*   ei    = (const int*)d_in[1];
    const int*   batch = (const int*)d_in[2];
    const float* W1    = (const float*)d_in[3];
    const float* asrc1 = (const float*)d_in[4];
    const float* adst1 = (const float*)d_in[5];
    const float* b1    = (const float*)d_in[6];
    const float* W2    = (const float*)d_in[7];
    const float* asrc2 = (const float*)d_in[8];
    const float* adst2 = (const float*)d_in[9];
    const float* b2    = (const float*)d_in[10];
    const float* fcW1  = (const float*)d_in[11];
    const float* fcb1  = (const float*)d_in[12];
    const float* fcW2  = (const float*)d_in[13];
    const float* fcb2  = (const float*)d_in[14];
    const float* fcW3  = (const float*)d_in[15];
    const float* fcb3  = (const float*)d_in[16];

    char* p = (char*)d_ws;
    auto take = [&](size_t bytes) {
        char* r = p;
        p += (bytes + 255) & ~(size_t)255;
        return r;
    };
    float* h    = (float*)take((size_t)N_NODES * CT * 4);   // 102.4 MB (h1 then h2)
    float* hx   = (float*)take((size_t)N_NODES * DE * 4);   // layer1 output
    float* as_  = (float*)take((size_t)N_NODES * NH * 4);
    float* ad_  = (float*)take((size_t)N_NODES * NH * 4);
    int*   ssrc = (int*)take((size_t)(N_EDGES + N_NODES) * 4);
    int*   offv = (int*)take((size_t)(N_NODES + 1) * 4);
    int*   cur  = (int*)take((size_t)N_NODES * 4);
    float* g0   = (float*)take((size_t)NG * DMLP * 4);
    float* g1   = (float*)take((size_t)NG * DMLP * 4);

    // CSR build (once; reused by both layers)
    init_count_k<<<(N_NODES + 255) / 256, 256, 0, stream>>>(cur);
    hist_k<<<(N_EDGES + 255) / 256, 256, 0, stream>>>(ei, cur);
    scan_k<<<1, 1024, 0, stream>>>(cur, offv);
    hipMemsetAsync(cur, 0, (size_t)N_NODES * 4, stream);
    scatter_k<<<(N_EDGES + N_NODES + 255) / 256, 256, 0, stream>>>(ei, offv, cur, ssrc);

    // Layer 1
    gemm_k<NF, false><<<(N_NODES + 15) / 16, 256, 0, stream>>>(x, W1, nullptr, h, N_NODES);
    alpha_k<<<(N_NODES * NH + 255) / 256, 256, 0, stream>>>(h, asrc1, adst1, as_, ad_);
    agg_wave_k<false><<<(N_NODES + 3) / 4, 256, 0, stream>>>(h, as_, ad_, ssrc, offv, b1, hx, nullptr, nullptr);

    // Layer 2 (h buffer reused; pooling fused into epilogue)
    gemm_k<DE, false><<<(N_NODES + 15) / 16, 256, 0, stream>>>(hx, W2, nullptr, h, N_NODES);
    alpha_k<<<(N_NODES * NH + 255) / 256, 256, 0, stream>>>(h, asrc2, adst2, as_, ad_);
    hipMemsetAsync(g0, 0, (size_t)NG * DMLP * 4, stream);
    agg_wave_k<true><<<(N_NODES + 3) / 4, 256, 0, stream>>>(h, as_, ad_, ssrc, offv, b2, nullptr, batch, g0);

    // MLP head
    gemm_k<DMLP, true><<<(NG + 15) / 16, 256, 0, stream>>>(g0, fcW1, fcb1, g1, NG);
    gemm_k<DMLP, true><<<(NG + 15) / 16, 256, 0, stream>>>(g1, fcW2, fcb2, g0, NG);
    mlp_out_k<<<(NG + 3) / 4, 256, 0, stream>>>(g0, fcW3, fcb3, (float*)d_out);
}

// Round 3
// 1314.254 us; speedup vs baseline: 1.2475x; 1.2475x over previous
//
#include <hip/hip_runtime.h>
#include <hip/hip_bf16.h>

#define N_NODES   50000
#define N_EDGES   800000
#define NF        32
#define DE        64
#define NH        8
#define CT        512     // NH*DE
#define DMLP      512
#define NG        2000
#define NEGS      0.2f

// ---------------- CSR build (shared by both GAT layers) ----------------

__global__ void init_count_k(int* __restrict__ cnt) {
    int i = blockIdx.x * 256 + threadIdx.x;
    if (i < N_NODES) cnt[i] = 1;   // start at 1: the self-loop
}

__global__ void hist_k(const int* __restrict__ ei, int* __restrict__ cnt) {
    int e = blockIdx.x * 256 + threadIdx.x;
    if (e < N_EDGES) atomicAdd(&cnt[ei[N_EDGES + e]], 1);   // row 1 = dst
}

// single-block exclusive scan over 50000 counts
__global__ void scan_k(const int* __restrict__ cnt, int* __restrict__ off) {
    __shared__ int buf[1024];
    __shared__ int carry;
    int tid = threadIdx.x;
    if (tid == 0) carry = 0;
    __syncthreads();
    for (int base = 0; base < N_NODES; base += 1024) {
        int v = (base + tid < N_NODES) ? cnt[base + tid] : 0;
        buf[tid] = v;
        __syncthreads();
        for (int d = 1; d < 1024; d <<= 1) {
            int t = (tid >= d) ? buf[tid - d] : 0;
            __syncthreads();
            buf[tid] += t;
            __syncthreads();
        }
        int incl = buf[tid];
        int c = carry;
        int tot = buf[1023];
        __syncthreads();
        if (base + tid < N_NODES) off[base + tid] = c + incl - v;
        if (tid == 0) carry = c + tot;
        __syncthreads();
    }
    if (tid == 0) off[N_NODES] = carry;
}

__global__ void scatter_k(const int* __restrict__ ei, const int* __restrict__ off,
                          int* __restrict__ cur, int* __restrict__ ssrc) {
    int e = blockIdx.x * 256 + threadIdx.x;
    if (e < N_EDGES) {
        int s = ei[e];
        int d = ei[N_EDGES + e];
        int p = off[d] + atomicAdd(&cur[d], 1);
        ssrc[p] = s;
    } else if (e < N_EDGES + N_NODES) {
        int i = e - N_EDGES;                    // self loop
        int p = off[i] + atomicAdd(&cur[i], 1);
        ssrc[p] = i;
    }
}

// ---------------- precompute: B = W·a per head (attention from raw input), U1 = W1/8 ----------------
// B1s/B1d: [32][8]  B2s/B2d: [64][8]  U1: [256][64] with U1[hd*32+c][f] = W1[c][hd*64+f]/8

__global__ void prep_k(const float* __restrict__ W1, const float* __restrict__ a_s1,
                       const float* __restrict__ a_d1, const float* __restrict__ W2,
                       const float* __restrict__ a_s2, const float* __restrict__ a_d2,
                       float* __restrict__ B1s, float* __restrict__ B1d,
                       float* __restrict__ B2s, float* __restrict__ B2d,
                       float* __restrict__ U1) {
    int idx = blockIdx.x * 256 + threadIdx.x;
    if (idx < 256) {                         // B1s/B1d
        int c = idx >> 3, hd = idx & 7;
        float s1 = 0.f, s2 = 0.f;
        for (int f = 0; f < 64; ++f) {
            float w = W1[c * 512 + hd * 64 + f];
            s1 += w * a_s1[hd * 64 + f];
            s2 += w * a_d1[hd * 64 + f];
        }
        B1s[idx] = s1; B1d[idx] = s2;
    } else if (idx < 768) {                  // B2s/B2d
        int i2 = idx - 256;
        int c = i2 >> 3, hd = i2 & 7;
        float s1 = 0.f, s2 = 0.f;
        for (int f = 0; f < 64; ++f) {
            float w = W2[c * 512 + hd * 64 + f];
            s1 += w * a_s2[hd * 64 + f];
            s2 += w * a_d2[hd * 64 + f];
        }
        B2s[i2] = s1; B2d[i2] = s2;
    } else if (idx < 768 + 256 * 64) {       // U1
        int i2 = idx - 768;
        int k = i2 >> 6, f = i2 & 63;
        int hd = k >> 5, c = k & 31;
        U1[i2] = W1[c * 512 + hd * 64 + f] * 0.125f;
    }
}

// ---------------- attention logits from raw features: as/ad[n,hd] = x[n,:] · B[:,hd] ----------------

template<int C>
__global__ void alpha_x_k(const float* __restrict__ xin, const float* __restrict__ Bs,
                          const float* __restrict__ Bd, float* __restrict__ as_,
                          float* __restrict__ ad_) {
    __shared__ float bs[C * 8], bd[C * 8];
    int tid = threadIdx.x;
    for (int i = tid; i < C * 8; i += 256) { bs[i] = Bs[i]; bd[i] = Bd[i]; }
    __syncthreads();
    int gid = blockIdx.x * 256 + tid;
    if (gid >= N_NODES * NH) return;
    int n = gid >> 3, hd = gid & 7;
    const float4* xp = (const float4*)(xin + (size_t)n * C);
    float s1 = 0.f, s2 = 0.f;
    #pragma unroll
    for (int q = 0; q < C / 4; ++q) {
        float4 v = xp[q];
        int b0 = (q * 4) * 8 + hd;
        s1 += v.x * bs[b0] + v.y * bs[b0 + 8] + v.z * bs[b0 + 16] + v.w * bs[b0 + 24];
        s2 += v.x * bd[b0] + v.y * bd[b0 + 8] + v.z * bd[b0 + 16] + v.w * bd[b0 + 24];
    }
    as_[gid] = s1;
    ad_[gid] = s2;
}

// ---------------- helpers ----------------

__device__ inline float4 fma4(float a, float4 v, float4 c) {
    c.x = fmaf(a, v.x, c.x); c.y = fmaf(a, v.y, c.y);
    c.z = fmaf(a, v.z, c.z); c.w = fmaf(a, v.w, c.w);
    return c;
}

__device__ inline float edge_w(float e) {
    e = e > 0.f ? e : NEGS * e;
    return __expf(e);      // no max-subtraction: ratio Σw·v / Σw is invariant
}

// ---------------- layer-1 aggregation over RAW x: aggx1[i, hd*32+c] = Σ_j α^hd x[j,c] / Σ_j α^hd ----
// one node per wave; lane: hd=lane>>3, owns x-channels [ (lane&7)*4, +4 ) → float4.
// All heads share the same x row read (HW dedups the 8-way broadcast) → 128B/edge.

__global__ __launch_bounds__(256) void agg1_k(
        const float* __restrict__ x, const float* __restrict__ as_,
        const float* __restrict__ ad_, const int* __restrict__ ssrc,
        const int* __restrict__ off, float* __restrict__ aggx1) {
    int wv = __builtin_amdgcn_readfirstlane(blockIdx.x * 4 + (threadIdx.x >> 6));
    if (wv >= N_NODES) return;
    int lane = threadIdx.x & 63;
    int hd = lane >> 3, q = lane & 7;
    int beg = off[wv], end = off[wv + 1];
    float adv = ad_[wv * NH + hd];

    float4 acc = {0.f, 0.f, 0.f, 0.f};
    float wsum = 0.f;
    int j = beg;
    for (; j + 4 <= end; j += 4) {
        int s0 = ssrc[j], s1 = ssrc[j + 1], s2 = ssrc[j + 2], s3 = ssrc[j + 3];
        float e0 = as_[s0 * NH + hd], e1 = as_[s1 * NH + hd];
        float e2 = as_[s2 * NH + hd], e3 = as_[s3 * NH + hd];
        float4 v0 = *(const float4*)(x + s0 * NF + q * 4);
        float4 v1 = *(const float4*)(x + s1 * NF + q * 4);
        float4 v2 = *(const float4*)(x + s2 * NF + q * 4);
        float4 v3 = *(const float4*)(x + s3 * NF + q * 4);
        float w0 = edge_w(e0 + adv), w1 = edge_w(e1 + adv);
        float w2 = edge_w(e2 + adv), w3 = edge_w(e3 + adv);
        wsum += (w0 + w1) + (w2 + w3);
        acc = fma4(w0, v0, acc); acc = fma4(w1, v1, acc);
        acc = fma4(w2, v2, acc); acc = fma4(w3, v3, acc);
    }
    for (; j < end; ++j) {
        int s0 = ssrc[j];
        float w0 = edge_w(as_[s0 * NH + hd] + adv);
        float4 v0 = *(const float4*)(x + s0 * NF + q * 4);
        wsum += w0;
        acc = fma4(w0, v0, acc);
    }
    float inv = 1.f / wsum;
    acc.x *= inv; acc.y *= inv; acc.z *= inv; acc.w *= inv;
    ((float4*)(aggx1 + (size_t)wv * 256))[lane] = acc;   // [hd*32 + q*4] == lane*4
}

// ---------------- layer-1 projection: hx[N,64] = aggx1[N,256] @ U1[256,64] + b1 -----------
// one row per wave, lane = output channel f.

__global__ __launch_bounds__(256) void proj1_k(
        const float* __restrict__ aggx1, const float* __restrict__ U1,
        const float* __restrict__ b1, float* __restrict__ hx) {
    int r = __builtin_amdgcn_readfirstlane(blockIdx.x * 4 + (threadIdx.x >> 6));
    if (r >= N_NODES) return;
    int f = threadIdx.x & 63;
    const float* ar = aggx1 + (size_t)r * 256;
    float acc = 0.f;
    #pragma unroll 4
    for (int k0 = 0; k0 < 256; k0 += 4) {
        float4 a = *(const float4*)(ar + k0);       // wave-uniform broadcast
        acc = fmaf(a.x, U1[(k0 + 0) * 64 + f], acc);
        acc = fmaf(a.y, U1[(k0 + 1) * 64 + f], acc);
        acc = fmaf(a.z, U1[(k0 + 2) * 64 + f], acc);
        acc = fmaf(a.w, U1[(k0 + 3) * 64 + f], acc);
    }
    hx[(size_t)r * 64 + f] = acc + b1[f];
}

// ---------------- layer-2 aggregation over hx + fused graph pooling ----------------
// per node: aggx2[hd, c] = Σ_j α^hd hx[j,c] / Σ α^hd  (c in [0,64))
// lane: hd=lane>>3, owns c ∈ [ (lane&7)*8, +8 ) → 2 float4 (8-way row share → 256B/edge).
// Epilogue scatters into P[batch[i], hd*64+c] with atomics; node count per graph too.

__global__ __launch_bounds__(256) void agg2_k(
        const float* __restrict__ hx, const float* __restrict__ as_,
        const float* __restrict__ ad_, const int* __restrict__ ssrc,
        const int* __restrict__ off, const int* __restrict__ batch,
        float* __restrict__ P, int* __restrict__ cntg) {
    int wv = __builtin_amdgcn_readfirstlane(blockIdx.x * 4 + (threadIdx.x >> 6));
    if (wv >= N_NODES) return;
    int lane = threadIdx.x & 63;
    int hd = lane >> 3, q = lane & 7;
    int beg = off[wv], end = off[wv + 1];
    float adv = ad_[wv * NH + hd];

    float4 a0 = {0.f, 0.f, 0.f, 0.f}, a1 = {0.f, 0.f, 0.f, 0.f};
    float wsum = 0.f;
    int j = beg;
    for (; j + 4 <= end; j += 4) {
        int s0 = ssrc[j], s1 = ssrc[j + 1], s2 = ssrc[j + 2], s3 = ssrc[j + 3];
        float e0 = as_[s0 * NH + hd], e1 = as_[s1 * NH + hd];
        float e2 = as_[s2 * NH + hd], e3 = as_[s3 * NH + hd];
        const float4* p0 = (const float4*)(hx + s0 * DE + q * 8);
        const float4* p1 = (const float4*)(hx + s1 * DE + q * 8);
        const float4* p2 = (const float4*)(hx + s2 * DE + q * 8);
        const float4* p3 = (const float4*)(hx + s3 * DE + q * 8);
        float4 v00 = p0[0], v01 = p0[1];
        float4 v10 = p1[0], v11 = p1[1];
        float4 v20 = p2[0], v21 = p2[1];
        float4 v30 = p3[0], v31 = p3[1];
        float w0 = edge_w(e0 + adv), w1 = edge_w(e1 + adv);
        float w2 = edge_w(e2 + adv), w3 = edge_w(e3 + adv);
        wsum += (w0 + w1) + (w2 + w3);
        a0 = fma4(w0, v00, a0); a1 = fma4(w0, v01, a1);
        a0 = fma4(w1, v10, a0); a1 = fma4(w1, v11, a1);
        a0 = fma4(w2, v20, a0); a1 = fma4(w2, v21, a1);
        a0 = fma4(w3, v30, a0); a1 = fma4(w3, v31, a1);
    }
    for (; j < end; ++j) {
        int s0 = ssrc[j];
        float w0 = edge_w(as_[s0 * NH + hd] + adv);
        const float4* p0 = (const float4*)(hx + s0 * DE + q * 8);
        float4 v00 = p0[0], v01 = p0[1];
        wsum += w0;
        a0 = fma4(w0, v00, a0); a1 = fma4(w0, v01, a1);
    }
    float inv = 1.f / wsum;
    int b = __builtin_amdgcn_readfirstlane(batch[wv]);
    float* gp = P + (size_t)b * CT + hd * 64 + q * 8;
    atomicAdd(gp + 0, a0.x * inv); atomicAdd(gp + 1, a0.y * inv);
    atomicAdd(gp + 2, a0.z * inv); atomicAdd(gp + 3, a0.w * inv);
    atomicAdd(gp + 4, a1.x * inv); atomicAdd(gp + 5, a1.y * inv);
    atomicAdd(gp + 6, a1.z * inv); atomicAdd(gp + 7, a1.w * inv);
    if (lane == 0) atomicAdd(&cntg[b], 1);
}

// ---------------- layer-2 projection on POOLED tensor: g0[b, hd*64+f] = P[b,hd,:]·W2[:,hd*64+f] + cnt·b2

__global__ void proj2_k(const float* __restrict__ P, const float* __restrict__ W2,
                        const float* __restrict__ b2, const int* __restrict__ cntg,
                        float* __restrict__ g0) {
    int gid = blockIdx.x * 256 + threadIdx.x;
    if (gid >= NG * CT) return;
    int b = gid >> 9, ch = gid & 511;
    int hd = ch >> 6, f = ch & 63;
    const float* Pp = P + (size_t)b * CT + hd * 64;
    float acc = (float)cntg[b] * b2[ch];
    #pragma unroll 4
    for (int c = 0; c < 64; ++c)
        acc = fmaf(Pp[c], W2[c * 512 + hd * 64 + f], acc);
    g0[gid] = acc;
}

// ---------------- MLP GEMM: Y[nrows,512] = relu(X[nrows,512] @ W + b) ----------------

template<int K>
__global__ void gemm_k(const float* __restrict__ X, const float* __restrict__ W,
                       const float* __restrict__ bias, float* __restrict__ Y, int nrows) {
    __shared__ float xs[16][K];
    int tid = threadIdx.x;
    int row0 = blockIdx.x * 16;
    for (int idx = tid; idx < 16 * K; idx += 256) {
        int r = idx / K, k = idx - r * K;
        int row = row0 + r;
        xs[r][k] = (row < nrows) ? X[(size_t)row * K + k] : 0.f;
    }
    __syncthreads();
    float acc0[16], acc1[16];
    #pragma unroll
    for (int r = 0; r < 16; ++r) { acc0[r] = 0.f; acc1[r] = 0.f; }
    for (int k = 0; k < K; ++k) {
        float w0 = W[(size_t)k * DMLP + tid];
        float w1 = W[(size_t)k * DMLP + tid + 256];
        #pragma unroll
        for (int r = 0; r < 16; ++r) {
            acc0[r] = fmaf(xs[r][k], w0, acc0[r]);
            acc1[r] = fmaf(xs[r][k], w1, acc1[r]);
        }
    }
    float b0 = bias[tid], b1 = bias[tid + 256];
    #pragma unroll
    for (int r = 0; r < 16; ++r) {
        int row = row0 + r;
        if (row < nrows) {
            Y[(size_t)row * DMLP + tid]       = fmaxf(acc0[r] + b0, 0.f);
            Y[(size_t)row * DMLP + tid + 256] = fmaxf(acc1[r] + b1, 0.f);
        }
    }
}

__global__ void mlp_out_k(const float* __restrict__ gin, const float* __restrict__ w,
                          const float* __restrict__ b, float* __restrict__ out) {
    int row = blockIdx.x * 4 + (threadIdx.x >> 6);
    int lane = threadIdx.x & 63;
    if (row >= NG) return;
    float s = 0.f;
    for (int k = lane; k < DMLP; k += 64) s += gin[(size_t)row * DMLP + k] * w[k];
    #pragma unroll
    for (int d = 32; d >= 1; d >>= 1) s += __shfl_xor(s, d, 64);
    if (lane == 0) out[row] = s + b[0];
}

// ---------------- launch ----------------

extern "C" void kernel_launch(void* const* d_in, const int* in_sizes, int n_in,
                              void* d_out, int out_size, void* d_ws, size_t ws_size,
                              hipStream_t stream) {
    const float* x     = (const float*)d_in[0];
    const int*   ei    = (const int*)d_in[1];
    const int*   batch = (const int*)d_in[2];
    const float* W1    = (const float*)d_in[3];
    const float* asrc1 = (const float*)d_in[4];
    const float* adst1 = (const float*)d_in[5];
    const float* b1    = (const float*)d_in[6];
    const float* W2    = (const float*)d_in[7];
    const float* asrc2 = (const float*)d_in[8];
    const float* adst2 = (const float*)d_in[9];
    const float* b2    = (const float*)d_in[10];
    const float* fcW1  = (const float*)d_in[11];
    const float* fcb1  = (const float*)d_in[12];
    const float* fcW2  = (const float*)d_in[13];
    const float* fcb2  = (const float*)d_in[14];
    const float* fcW3  = (const float*)d_in[15];
    const float* fcb3  = (const float*)d_in[16];

    char* p = (char*)d_ws;
    auto take = [&](size_t bytes) {
        char* r = p;
        p += (bytes + 255) & ~(size_t)255;
        return r;
    };
    float* aggx1 = (float*)take((size_t)N_NODES * 256 * 4);  // 51.2 MB
    float* hx    = (float*)take((size_t)N_NODES * DE * 4);   // 12.8 MB
    float* as_   = (float*)take((size_t)N_NODES * NH * 4);
    float* ad_   = (float*)take((size_t)N_NODES * NH * 4);
    int*   ssrc  = (int*)take((size_t)(N_EDGES + N_NODES) * 4);
    int*   offv  = (int*)take((size_t)(N_NODES + 1) * 4);
    int*   cur   = (int*)take((size_t)N_NODES * 4);
    float* B1s   = (float*)take(256 * 4);
    float* B1d   = (float*)take(256 * 4);
    float* B2s   = (float*)take(512 * 4);
    float* B2d   = (float*)take(512 * 4);
    float* U1    = (float*)take(256 * 64 * 4);
    float* P     = (float*)take((size_t)NG * CT * 4);        // pooled per-head agg
    int*   cntg  = (int*)take((size_t)NG * 4);
    float* g0    = (float*)take((size_t)NG * DMLP * 4);
    float* g1    = (float*)take((size_t)NG * DMLP * 4);

    // CSR build (once; reused by both layers)
    init_count_k<<<(N_NODES + 255) / 256, 256, 0, stream>>>(cur);
    hist_k<<<(N_EDGES + 255) / 256, 256, 0, stream>>>(ei, cur);
    scan_k<<<1, 1024, 0, stream>>>(cur, offv);
    hipMemsetAsync(cur, 0, (size_t)N_NODES * 4, stream);
    scatter_k<<<(N_EDGES + N_NODES + 255) / 256, 256, 0, stream>>>(ei, offv, cur, ssrc);

    // weight precompute
    prep_k<<<(768 + 256 * 64 + 255) / 256, 256, 0, stream>>>(
        W1, asrc1, adst1, W2, asrc2, adst2, B1s, B1d, B2s, B2d, U1);

    // Layer 1: logits from x, aggregate x per head, then project
    alpha_x_k<NF><<<(N_NODES * NH + 255) / 256, 256, 0, stream>>>(x, B1s, B1d, as_, ad_);
    agg1_k<<<(N_NODES + 3) / 4, 256, 0, stream>>>(x, as_, ad_, ssrc, offv, aggx1);
    proj1_k<<<(N_NODES + 3) / 4, 256, 0, stream>>>(aggx1, U1, b1, hx);

    // Layer 2: logits from hx, aggregate hx per head + fused pooling, project pooled
    alpha_x_k<DE><<<(N_NODES * NH + 255) / 256, 256, 0, stream>>>(hx, B2s, B2d, as_, ad_);
    hipMemsetAsync(P, 0, (size_t)NG * CT * 4, stream);
    hipMemsetAsync(cntg, 0, (size_t)NG * 4, stream);
    agg2_k<<<(N_NODES + 3) / 4, 256, 0, stream>>>(hx, as_, ad_, ssrc, offv, batch, P, cntg);
    proj2_k<<<(NG * CT + 255) / 256, 256, 0, stream>>>(P, W2, b2, cntg, g0);

    // MLP head
    gemm_k<DMLP><<<(NG + 15) / 16, 256, 0, stream>>>(g0, fcW1, fcb1, g1, NG);
    gemm_k<DMLP><<<(NG + 15) / 16, 256, 0, stream>>>(g1, fcW2, fcb2, g0, NG);
    mlp_out_k<<<(NG + 3) / 4, 256, 0, stream>>>(g0, fcW3, fcb3, (float*)d_out);
}

// Round 4
// 674.130 us; speedup vs baseline: 2.4321x; 1.9496x over previous
//
#include <hip/hip_runtime.h>
#include <hip/hip_bf16.h>

#define N_NODES   50000
#define N_EDGES   800000
#define NF        32
#define DE        64
#define NH        8
#define CT        512     // NH*DE
#define DMLP      512
#define NG        2000
#define NEGS      0.2f

// ---------------- CSR build (shared by both GAT layers) ----------------

__global__ void init_count_k(int* __restrict__ cnt) {
    int i = blockIdx.x * 256 + threadIdx.x;
    if (i < N_NODES) cnt[i] = 1;   // start at 1: the self-loop
}

__global__ void hist_k(const int* __restrict__ ei, int* __restrict__ cnt) {
    int e = blockIdx.x * 256 + threadIdx.x;
    if (e < N_EDGES) atomicAdd(&cnt[ei[N_EDGES + e]], 1);   // row 1 = dst
}

// single-block exclusive scan over 50000 counts
__global__ void scan_k(const int* __restrict__ cnt, int* __restrict__ off) {
    __shared__ int buf[1024];
    __shared__ int carry;
    int tid = threadIdx.x;
    if (tid == 0) carry = 0;
    __syncthreads();
    for (int base = 0; base < N_NODES; base += 1024) {
        int v = (base + tid < N_NODES) ? cnt[base + tid] : 0;
        buf[tid] = v;
        __syncthreads();
        for (int d = 1; d < 1024; d <<= 1) {
            int t = (tid >= d) ? buf[tid - d] : 0;
            __syncthreads();
            buf[tid] += t;
            __syncthreads();
        }
        int incl = buf[tid];
        int c = carry;
        int tot = buf[1023];
        __syncthreads();
        if (base + tid < N_NODES) off[base + tid] = c + incl - v;
        if (tid == 0) carry = c + tot;
        __syncthreads();
    }
    if (tid == 0) off[N_NODES] = carry;
}

__global__ void scatter_k(const int* __restrict__ ei, const int* __restrict__ off,
                          int* __restrict__ cur, int* __restrict__ ssrc) {
    int e = blockIdx.x * 256 + threadIdx.x;
    if (e < N_EDGES) {
        int s = ei[e];
        int d = ei[N_EDGES + e];
        int p = off[d] + atomicAdd(&cur[d], 1);
        ssrc[p] = s;
    } else if (e < N_EDGES + N_NODES) {
        int i = e - N_EDGES;                    // self loop
        int p = off[i] + atomicAdd(&cur[i], 1);
        ssrc[p] = i;
    }
}

// ---------------- graph offsets from sorted batch: goff[g] = first node with batch>=g ----

__global__ void goffs_k(const int* __restrict__ batch, int* __restrict__ goff) {
    int i = blockIdx.x * 256 + threadIdx.x;
    if (i >= N_NODES) return;
    int b = batch[i];
    if (i == 0) {
        for (int g = 0; g <= b; ++g) goff[g] = 0;
    } else {
        int pb = batch[i - 1];
        for (int g = pb + 1; g <= b; ++g) goff[g] = i;
    }
    if (i == N_NODES - 1) {
        for (int g = b + 1; g <= NG; ++g) goff[g] = N_NODES;
    }
}

// ---------------- precompute: B = W·a per head (attention from raw input), U1 = W1/8 ----------------
// B1s/B1d: [32][8]  B2s/B2d: [64][8]  U1: [256][64] with U1[hd*32+c][f] = W1[c][hd*64+f]/8

__global__ void prep_k(const float* __restrict__ W1, const float* __restrict__ a_s1,
                       const float* __restrict__ a_d1, const float* __restrict__ W2,
                       const float* __restrict__ a_s2, const float* __restrict__ a_d2,
                       float* __restrict__ B1s, float* __restrict__ B1d,
                       float* __restrict__ B2s, float* __restrict__ B2d,
                       float* __restrict__ U1) {
    int idx = blockIdx.x * 256 + threadIdx.x;
    if (idx < 256) {                         // B1s/B1d
        int c = idx >> 3, hd = idx & 7;
        float s1 = 0.f, s2 = 0.f;
        for (int f = 0; f < 64; ++f) {
            float w = W1[c * 512 + hd * 64 + f];
            s1 += w * a_s1[hd * 64 + f];
            s2 += w * a_d1[hd * 64 + f];
        }
        B1s[idx] = s1; B1d[idx] = s2;
    } else if (idx < 768) {                  // B2s/B2d
        int i2 = idx - 256;
        int c = i2 >> 3, hd = i2 & 7;
        float s1 = 0.f, s2 = 0.f;
        for (int f = 0; f < 64; ++f) {
            float w = W2[c * 512 + hd * 64 + f];
            s1 += w * a_s2[hd * 64 + f];
            s2 += w * a_d2[hd * 64 + f];
        }
        B2s[i2] = s1; B2d[i2] = s2;
    } else if (idx < 768 + 256 * 64) {       // U1
        int i2 = idx - 768;
        int k = i2 >> 6, f = i2 & 63;
        int hd = k >> 5, c = k & 31;
        U1[i2] = W1[c * 512 + hd * 64 + f] * 0.125f;
    }
}

// ---------------- attention logits from raw features: as/ad[n,hd] = x[n,:] · B[:,hd] ----------------

template<int C>
__global__ void alpha_x_k(const float* __restrict__ xin, const float* __restrict__ Bs,
                          const float* __restrict__ Bd, float* __restrict__ as_,
                          float* __restrict__ ad_) {
    __shared__ float bs[C * 8], bd[C * 8];
    int tid = threadIdx.x;
    for (int i = tid; i < C * 8; i += 256) { bs[i] = Bs[i]; bd[i] = Bd[i]; }
    __syncthreads();
    int gid = blockIdx.x * 256 + tid;
    if (gid >= N_NODES * NH) return;
    int n = gid >> 3, hd = gid & 7;
    const float4* xp = (const float4*)(xin + (size_t)n * C);
    float s1 = 0.f, s2 = 0.f;
    #pragma unroll
    for (int q = 0; q < C / 4; ++q) {
        float4 v = xp[q];
        int b0 = (q * 4) * 8 + hd;
        s1 += v.x * bs[b0] + v.y * bs[b0 + 8] + v.z * bs[b0 + 16] + v.w * bs[b0 + 24];
        s2 += v.x * bd[b0] + v.y * bd[b0 + 8] + v.z * bd[b0 + 16] + v.w * bd[b0 + 24];
    }
    as_[gid] = s1;
    ad_[gid] = s2;
}

// ---------------- helpers ----------------

__device__ inline float4 fma4(float a, float4 v, float4 c) {
    c.x = fmaf(a, v.x, c.x); c.y = fmaf(a, v.y, c.y);
    c.z = fmaf(a, v.z, c.z); c.w = fmaf(a, v.w, c.w);
    return c;
}

__device__ inline float edge_w(float e) {
    e = e > 0.f ? e : NEGS * e;
    return __expf(e);      // no max-subtraction: ratio Σw·v / Σw is invariant
}

// ---------------- layer-1 aggregation over RAW x: aggx1[i, hd*32+c] = Σ_j α^hd x[j,c] / Σ_j α^hd ----

__global__ __launch_bounds__(256) void agg1_k(
        const float* __restrict__ x, const float* __restrict__ as_,
        const float* __restrict__ ad_, const int* __restrict__ ssrc,
        const int* __restrict__ off, float* __restrict__ aggx1) {
    int wv = __builtin_amdgcn_readfirstlane(blockIdx.x * 4 + (threadIdx.x >> 6));
    if (wv >= N_NODES) return;
    int lane = threadIdx.x & 63;
    int hd = lane >> 3, q = lane & 7;
    int beg = off[wv], end = off[wv + 1];
    float adv = ad_[wv * NH + hd];

    float4 acc = {0.f, 0.f, 0.f, 0.f};
    float wsum = 0.f;
    int j = beg;
    for (; j + 4 <= end; j += 4) {
        int s0 = ssrc[j], s1 = ssrc[j + 1], s2 = ssrc[j + 2], s3 = ssrc[j + 3];
        float e0 = as_[s0 * NH + hd], e1 = as_[s1 * NH + hd];
        float e2 = as_[s2 * NH + hd], e3 = as_[s3 * NH + hd];
        float4 v0 = *(const float4*)(x + s0 * NF + q * 4);
        float4 v1 = *(const float4*)(x + s1 * NF + q * 4);
        float4 v2 = *(const float4*)(x + s2 * NF + q * 4);
        float4 v3 = *(const float4*)(x + s3 * NF + q * 4);
        float w0 = edge_w(e0 + adv), w1 = edge_w(e1 + adv);
        float w2 = edge_w(e2 + adv), w3 = edge_w(e3 + adv);
        wsum += (w0 + w1) + (w2 + w3);
        acc = fma4(w0, v0, acc); acc = fma4(w1, v1, acc);
        acc = fma4(w2, v2, acc); acc = fma4(w3, v3, acc);
    }
    for (; j < end; ++j) {
        int s0 = ssrc[j];
        float w0 = edge_w(as_[s0 * NH + hd] + adv);
        float4 v0 = *(const float4*)(x + s0 * NF + q * 4);
        wsum += w0;
        acc = fma4(w0, v0, acc);
    }
    float inv = 1.f / wsum;
    acc.x *= inv; acc.y *= inv; acc.z *= inv; acc.w *= inv;
    ((float4*)(aggx1 + (size_t)wv * 256))[lane] = acc;   // [hd*32 + q*4] == lane*4
}

// ---------------- layer-1 projection: hx[N,64] = aggx1[N,256] @ U1[256,64] + b1 -----------

__global__ __launch_bounds__(256) void proj1_k(
        const float* __restrict__ aggx1, const float* __restrict__ U1,
        const float* __restrict__ b1, float* __restrict__ hx) {
    int r = __builtin_amdgcn_readfirstlane(blockIdx.x * 4 + (threadIdx.x >> 6));
    if (r >= N_NODES) return;
    int f = threadIdx.x & 63;
    const float* ar = aggx1 + (size_t)r * 256;
    float acc = 0.f;
    #pragma unroll 4
    for (int k0 = 0; k0 < 256; k0 += 4) {
        float4 a = *(const float4*)(ar + k0);       // wave-uniform broadcast
        acc = fmaf(a.x, U1[(k0 + 0) * 64 + f], acc);
        acc = fmaf(a.y, U1[(k0 + 1) * 64 + f], acc);
        acc = fmaf(a.z, U1[(k0 + 2) * 64 + f], acc);
        acc = fmaf(a.w, U1[(k0 + 3) * 64 + f], acc);
    }
    hx[(size_t)r * 64 + f] = acc + b1[f];
}

// ---------------- layer-2 aggregation + pooling: ONE BLOCK PER GRAPH, zero atomics ----------
// Wave w handles nodes goff[g]+w, +4, ... Per node: edge loop over CSR, normalized per-head
// weighted mean of hx rows; accumulate into per-lane registers. Cross-wave combine via LDS,
// block writes P[g, 512] with plain stores.

__global__ __launch_bounds__(256) void agg2g_k(
        const float* __restrict__ hx, const float* __restrict__ as_,
        const float* __restrict__ ad_, const int* __restrict__ ssrc,
        const int* __restrict__ off, const int* __restrict__ goff,
        float* __restrict__ P) {
    int g = blockIdx.x;
    int w = threadIdx.x >> 6;
    int lane = threadIdx.x & 63;
    int hd = lane >> 3, q = lane & 7;
    int nbeg = goff[g], nend = goff[g + 1];

    __shared__ float sp[4][512];

    float4 p0 = {0.f, 0.f, 0.f, 0.f}, p1 = {0.f, 0.f, 0.f, 0.f};

    for (int nd0 = nbeg + w; nd0 < nend; nd0 += 4) {
        int nd = __builtin_amdgcn_readfirstlane(nd0);
        int beg = off[nd], end = off[nd + 1];
        float adv = ad_[nd * NH + hd];

        float4 a0 = {0.f, 0.f, 0.f, 0.f}, a1 = {0.f, 0.f, 0.f, 0.f};
        float wsum = 0.f;
        int j = beg;
        for (; j + 4 <= end; j += 4) {
            int s0 = ssrc[j], s1 = ssrc[j + 1], s2 = ssrc[j + 2], s3 = ssrc[j + 3];
            float e0 = as_[s0 * NH + hd], e1 = as_[s1 * NH + hd];
            float e2 = as_[s2 * NH + hd], e3 = as_[s3 * NH + hd];
            const float4* pp0 = (const float4*)(hx + s0 * DE + q * 8);
            const float4* pp1 = (const float4*)(hx + s1 * DE + q * 8);
            const float4* pp2 = (const float4*)(hx + s2 * DE + q * 8);
            const float4* pp3 = (const float4*)(hx + s3 * DE + q * 8);
            float4 v00 = pp0[0], v01 = pp0[1];
            float4 v10 = pp1[0], v11 = pp1[1];
            float4 v20 = pp2[0], v21 = pp2[1];
            float4 v30 = pp3[0], v31 = pp3[1];
            float w0 = edge_w(e0 + adv), w1 = edge_w(e1 + adv);
            float w2 = edge_w(e2 + adv), w3 = edge_w(e3 + adv);
            wsum += (w0 + w1) + (w2 + w3);
            a0 = fma4(w0, v00, a0); a1 = fma4(w0, v01, a1);
            a0 = fma4(w1, v10, a0); a1 = fma4(w1, v11, a1);
            a0 = fma4(w2, v20, a0); a1 = fma4(w2, v21, a1);
            a0 = fma4(w3, v30, a0); a1 = fma4(w3, v31, a1);
        }
        for (; j < end; ++j) {
            int s0 = ssrc[j];
            float w0 = edge_w(as_[s0 * NH + hd] + adv);
            const float4* pp0 = (const float4*)(hx + s0 * DE + q * 8);
            float4 v00 = pp0[0], v01 = pp0[1];
            wsum += w0;
            a0 = fma4(w0, v00, a0); a1 = fma4(w0, v01, a1);
        }
        float inv = 1.f / wsum;
        p0 = fma4(inv, a0, p0);
        p1 = fma4(inv, a1, p1);
    }

    // combine 4 waves via LDS; channel layout: hd*64 + q*8 + m
    ((float4*)&sp[w][lane * 8])[0] = p0;
    ((float4*)&sp[w][lane * 8 + 4])[0] = p1;
    __syncthreads();
    int t = threadIdx.x;
    float s0 = sp[0][t] + sp[1][t] + sp[2][t] + sp[3][t];
    float s1 = sp[0][t + 256] + sp[1][t + 256] + sp[2][t + 256] + sp[3][t + 256];
    P[(size_t)g * CT + t]       = s0;
    P[(size_t)g * CT + t + 256] = s1;
}

// ---------------- layer-2 projection on POOLED tensor: g0[b, hd*64+f] = P[b,hd,:]·W2[:,hd*64+f] + cnt·b2

__global__ void proj2_k(const float* __restrict__ P, const float* __restrict__ W2,
                        const float* __restrict__ b2, const int* __restrict__ goff,
                        float* __restrict__ g0) {
    int gid = blockIdx.x * 256 + threadIdx.x;
    if (gid >= NG * CT) return;
    int b = gid >> 9, ch = gid & 511;
    int hd = ch >> 6, f = ch & 63;
    const float* Pp = P + (size_t)b * CT + hd * 64;
    int cnt = goff[b + 1] - goff[b];
    float acc = (float)cnt * b2[ch];
    #pragma unroll 4
    for (int c = 0; c < 64; ++c)
        acc = fmaf(Pp[c], W2[c * 512 + hd * 64 + f], acc);
    g0[gid] = acc;
}

// ---------------- MLP GEMM: Y[nrows,512] = relu(X[nrows,512] @ W + b) ----------------

template<int K>
__global__ void gemm_k(const float* __restrict__ X, const float* __restrict__ W,
                       const float* __restrict__ bias, float* __restrict__ Y, int nrows) {
    __shared__ float xs[16][K];
    int tid = threadIdx.x;
    int row0 = blockIdx.x * 16;
    for (int idx = tid; idx < 16 * K; idx += 256) {
        int r = idx / K, k = idx - r * K;
        int row = row0 + r;
        xs[r][k] = (row < nrows) ? X[(size_t)row * K + k] : 0.f;
    }
    __syncthreads();
    float acc0[16], acc1[16];
    #pragma unroll
    for (int r = 0; r < 16; ++r) { acc0[r] = 0.f; acc1[r] = 0.f; }
    for (int k = 0; k < K; ++k) {
        float w0 = W[(size_t)k * DMLP + tid];
        float w1 = W[(size_t)k * DMLP + tid + 256];
        #pragma unroll
        for (int r = 0; r < 16; ++r) {
            acc0[r] = fmaf(xs[r][k], w0, acc0[r]);
            acc1[r] = fmaf(xs[r][k], w1, acc1[r]);
        }
    }
    float b0 = bias[tid], b1 = bias[tid + 256];
    #pragma unroll
    for (int r = 0; r < 16; ++r) {
        int row = row0 + r;
        if (row < nrows) {
            Y[(size_t)row * DMLP + tid]       = fmaxf(acc0[r] + b0, 0.f);
            Y[(size_t)row * DMLP + tid + 256] = fmaxf(acc1[r] + b1, 0.f);
        }
    }
}

__global__ void mlp_out_k(const float* __restrict__ gin, const float* __restrict__ w,
                          const float* __restrict__ b, float* __restrict__ out) {
    int row = blockIdx.x * 4 + (threadIdx.x >> 6);
    int lane = threadIdx.x & 63;
    if (row >= NG) return;
    float s = 0.f;
    for (int k = lane; k < DMLP; k += 64) s += gin[(size_t)row * DMLP + k] * w[k];
    #pragma unroll
    for (int d = 32; d >= 1; d >>= 1) s += __shfl_xor(s, d, 64);
    if (lane == 0) out[row] = s + b[0];
}

// ---------------- launch ----------------

extern "C" void kernel_launch(void* const* d_in, const int* in_sizes, int n_in,
                              void* d_out, int out_size, void* d_ws, size_t ws_size,
                              hipStream_t stream) {
    const float* x     = (const float*)d_in[0];
    const int*   ei    = (const int*)d_in[1];
    const int*   batch = (const int*)d_in[2];
    const float* W1    = (const float*)d_in[3];
    const float* asrc1 = (const float*)d_in[4];
    const float* adst1 = (const float*)d_in[5];
    const float* b1    = (const float*)d_in[6];
    const float* W2    = (const float*)d_in[7];
    const float* asrc2 = (const float*)d_in[8];
    const float* adst2 = (const float*)d_in[9];
    const float* b2    = (const float*)d_in[10];
    const float* fcW1  = (const float*)d_in[11];
    const float* fcb1  = (const float*)d_in[12];
    const float* fcW2  = (const float*)d_in[13];
    const float* fcb2  = (const float*)d_in[14];
    const float* fcW3  = (const float*)d_in[15];
    const float* fcb3  = (const float*)d_in[16];

    char* p = (char*)d_ws;
    auto take = [&](size_t bytes) {
        char* r = p;
        p += (bytes + 255) & ~(size_t)255;
        return r;
    };
    float* aggx1 = (float*)take((size_t)N_NODES * 256 * 4);  // 51.2 MB
    float* hx    = (float*)take((size_t)N_NODES * DE * 4);   // 12.8 MB
    float* as_   = (float*)take((size_t)N_NODES * NH * 4);
    float* ad_   = (float*)take((size_t)N_NODES * NH * 4);
    int*   ssrc  = (int*)take((size_t)(N_EDGES + N_NODES) * 4);
    int*   offv  = (int*)take((size_t)(N_NODES + 1) * 4);
    int*   cur   = (int*)take((size_t)N_NODES * 4);
    int*   goff  = (int*)take((size_t)(NG + 1) * 4);
    float* B1s   = (float*)take(256 * 4);
    float* B1d   = (float*)take(256 * 4);
    float* B2s   = (float*)take(512 * 4);
    float* B2d   = (float*)take(512 * 4);
    float* U1    = (float*)take(256 * 64 * 4);
    float* P     = (float*)take((size_t)NG * CT * 4);        // pooled per-head agg
    float* g0    = (float*)take((size_t)NG * DMLP * 4);
    float* g1    = (float*)take((size_t)NG * DMLP * 4);

    // CSR build (once; reused by both layers) + graph offsets
    init_count_k<<<(N_NODES + 255) / 256, 256, 0, stream>>>(cur);
    hist_k<<<(N_EDGES + 255) / 256, 256, 0, stream>>>(ei, cur);
    scan_k<<<1, 1024, 0, stream>>>(cur, offv);
    hipMemsetAsync(cur, 0, (size_t)N_NODES * 4, stream);
    scatter_k<<<(N_EDGES + N_NODES + 255) / 256, 256, 0, stream>>>(ei, offv, cur, ssrc);
    goffs_k<<<(N_NODES + 255) / 256, 256, 0, stream>>>(batch, goff);

    // weight precompute
    prep_k<<<(768 + 256 * 64 + 255) / 256, 256, 0, stream>>>(
        W1, asrc1, adst1, W2, asrc2, adst2, B1s, B1d, B2s, B2d, U1);

    // Layer 1: logits from x, aggregate x per head, then project
    alpha_x_k<NF><<<(N_NODES * NH + 255) / 256, 256, 0, stream>>>(x, B1s, B1d, as_, ad_);
    agg1_k<<<(N_NODES + 3) / 4, 256, 0, stream>>>(x, as_, ad_, ssrc, offv, aggx1);
    proj1_k<<<(N_NODES + 3) / 4, 256, 0, stream>>>(aggx1, U1, b1, hx);

    // Layer 2: logits from hx, block-per-graph aggregate+pool (no atomics), project pooled
    alpha_x_k<DE><<<(N_NODES * NH + 255) / 256, 256, 0, stream>>>(hx, B2s, B2d, as_, ad_);
    agg2g_k<<<NG, 256, 0, stream>>>(hx, as_, ad_, ssrc, offv, goff, P);
    proj2_k<<<(NG * CT + 255) / 256, 256, 0, stream>>>(P, W2, b2, goff, g0);

    // MLP head
    gemm_k<DMLP><<<(NG + 15) / 16, 256, 0, stream>>>(g0, fcW1, fcb1, g1, NG);
    gemm_k<DMLP><<<(NG + 15) / 16, 256, 0, stream>>>(g1, fcW2, fcb2, g0, NG);
    mlp_out_k<<<(NG + 3) / 4, 256, 0, stream>>>(g0, fcW3, fcb3, (float*)d_out);
}

// Round 5
// 409.864 us; speedup vs baseline: 4.0002x; 1.6448x over previous
//
#include <hip/hip_runtime.h>
#include <hip/hip_bf16.h>

#define N_NODES   50000
#define N_EDGES   800000
#define NF        32
#define DE        64
#define NH        8
#define CT        512     // NH*DE
#define DMLP      512
#define NG        2000
#define NEGS      0.2f

// ---------------- CSR build (shared by both GAT layers) ----------------

__global__ void init_count_k(int* __restrict__ cnt) {
    int i = blockIdx.x * 256 + threadIdx.x;
    if (i < N_NODES) cnt[i] = 1;   // start at 1: the self-loop
}

__global__ void hist_k(const int* __restrict__ ei, int* __restrict__ cnt) {
    int e = blockIdx.x * 256 + threadIdx.x;
    if (e < N_EDGES) atomicAdd(&cnt[ei[N_EDGES + e]], 1);   // row 1 = dst
}

// range allocation: off[i] = atomicAdd(total, cnt[i]).  Segment placement is
// run-varying but each node's edge multiset is identical -> output invariant.
__global__ void alloc_off_k(const int* __restrict__ cnt, int* __restrict__ off,
                            int* __restrict__ total) {
    int i = blockIdx.x * 256 + threadIdx.x;
    if (i < N_NODES) off[i] = atomicAdd(total, cnt[i]);
}

__global__ void scatter_k(const int* __restrict__ ei, const int* __restrict__ off,
                          int* __restrict__ cur, int* __restrict__ ssrc) {
    int e = blockIdx.x * 256 + threadIdx.x;
    if (e < N_EDGES) {
        int s = ei[e];
        int d = ei[N_EDGES + e];
        int p = off[d] + atomicAdd(&cur[d], 1);
        ssrc[p] = s;
    } else if (e < N_EDGES + N_NODES) {
        int i = e - N_EDGES;                    // self loop
        int p = off[i] + atomicAdd(&cur[i], 1);
        ssrc[p] = i;
    }
}

// ---------------- graph offsets from sorted batch: goff[g] = first node with batch>=g ----

__global__ void goffs_k(const int* __restrict__ batch, int* __restrict__ goff) {
    int i = blockIdx.x * 256 + threadIdx.x;
    if (i >= N_NODES) return;
    int b = batch[i];
    if (i == 0) {
        for (int g = 0; g <= b; ++g) goff[g] = 0;
    } else {
        int pb = batch[i - 1];
        for (int g = pb + 1; g <= b; ++g) goff[g] = i;
    }
    if (i == N_NODES - 1) {
        for (int g = b + 1; g <= NG; ++g) goff[g] = N_NODES;
    }
}

// ---------------- precompute: B = W·a per head, U1 = W1/8 (head-mean folded) ----------------

__global__ void prep_k(const float* __restrict__ W1, const float* __restrict__ a_s1,
                       const float* __restrict__ a_d1, const float* __restrict__ W2,
                       const float* __restrict__ a_s2, const float* __restrict__ a_d2,
                       float* __restrict__ B1s, float* __restrict__ B1d,
                       float* __restrict__ B2s, float* __restrict__ B2d,
                       float* __restrict__ U1) {
    int idx = blockIdx.x * 256 + threadIdx.x;
    if (idx < 256) {                         // B1s/B1d
        int c = idx >> 3, hd = idx & 7;
        float s1 = 0.f, s2 = 0.f;
        for (int f = 0; f < 64; ++f) {
            float w = W1[c * 512 + hd * 64 + f];
            s1 += w * a_s1[hd * 64 + f];
            s2 += w * a_d1[hd * 64 + f];
        }
        B1s[idx] = s1; B1d[idx] = s2;
    } else if (idx < 768) {                  // B2s/B2d
        int i2 = idx - 256;
        int c = i2 >> 3, hd = i2 & 7;
        float s1 = 0.f, s2 = 0.f;
        for (int f = 0; f < 64; ++f) {
            float w = W2[c * 512 + hd * 64 + f];
            s1 += w * a_s2[hd * 64 + f];
            s2 += w * a_d2[hd * 64 + f];
        }
        B2s[i2] = s1; B2d[i2] = s2;
    } else if (idx < 768 + 256 * 64) {       // U1[hd*32+c][f] = W1[c][hd*64+f]/8
        int i2 = idx - 768;
        int k = i2 >> 6, f = i2 & 63;
        int hd = k >> 5, c = k & 31;
        U1[i2] = W1[c * 512 + hd * 64 + f] * 0.125f;
    }
}

// ---------------- attention logits from raw features: as/ad[n,hd] = x[n,:] · B[:,hd] ----------------

template<int C>
__global__ void alpha_x_k(const float* __restrict__ xin, const float* __restrict__ Bs,
                          const float* __restrict__ Bd, float* __restrict__ as_,
                          float* __restrict__ ad_) {
    __shared__ float bs[C * 8], bd[C * 8];
    int tid = threadIdx.x;
    for (int i = tid; i < C * 8; i += 256) { bs[i] = Bs[i]; bd[i] = Bd[i]; }
    __syncthreads();
    int gid = blockIdx.x * 256 + tid;
    if (gid >= N_NODES * NH) return;
    int n = gid >> 3, hd = gid & 7;
    const float4* xp = (const float4*)(xin + (size_t)n * C);
    float s1 = 0.f, s2 = 0.f;
    #pragma unroll
    for (int q = 0; q < C / 4; ++q) {
        float4 v = xp[q];
        int b0 = (q * 4) * 8 + hd;
        s1 += v.x * bs[b0] + v.y * bs[b0 + 8] + v.z * bs[b0 + 16] + v.w * bs[b0 + 24];
        s2 += v.x * bd[b0] + v.y * bd[b0 + 8] + v.z * bd[b0 + 16] + v.w * bd[b0 + 24];
    }
    as_[gid] = s1;
    ad_[gid] = s2;
}

// ---------------- helpers ----------------

__device__ inline float4 fma4(float a, float4 v, float4 c) {
    c.x = fmaf(a, v.x, c.x); c.y = fmaf(a, v.y, c.y);
    c.z = fmaf(a, v.z, c.z); c.w = fmaf(a, v.w, c.w);
    return c;
}

__device__ inline float edge_w(float e) {
    e = e > 0.f ? e : NEGS * e;
    return __expf(e);      // no max-subtraction: ratio Σw·v / Σw is invariant
}

// ---------------- layer-1 aggregation over RAW x ----------------

__global__ __launch_bounds__(256) void agg1_k(
        const float* __restrict__ x, const float* __restrict__ as_,
        const float* __restrict__ ad_, const int* __restrict__ ssrc,
        const int* __restrict__ off, const int* __restrict__ cnt,
        float* __restrict__ aggx1) {
    int wv = __builtin_amdgcn_readfirstlane(blockIdx.x * 4 + (threadIdx.x >> 6));
    if (wv >= N_NODES) return;
    int lane = threadIdx.x & 63;
    int hd = lane >> 3, q = lane & 7;
    int beg = off[wv], end = beg + cnt[wv];
    float adv = ad_[wv * NH + hd];

    float4 acc = {0.f, 0.f, 0.f, 0.f};
    float wsum = 0.f;
    int j = beg;
    for (; j + 4 <= end; j += 4) {
        int s0 = ssrc[j], s1 = ssrc[j + 1], s2 = ssrc[j + 2], s3 = ssrc[j + 3];
        float e0 = as_[s0 * NH + hd], e1 = as_[s1 * NH + hd];
        float e2 = as_[s2 * NH + hd], e3 = as_[s3 * NH + hd];
        float4 v0 = *(const float4*)(x + s0 * NF + q * 4);
        float4 v1 = *(const float4*)(x + s1 * NF + q * 4);
        float4 v2 = *(const float4*)(x + s2 * NF + q * 4);
        float4 v3 = *(const float4*)(x + s3 * NF + q * 4);
        float w0 = edge_w(e0 + adv), w1 = edge_w(e1 + adv);
        float w2 = edge_w(e2 + adv), w3 = edge_w(e3 + adv);
        wsum += (w0 + w1) + (w2 + w3);
        acc = fma4(w0, v0, acc); acc = fma4(w1, v1, acc);
        acc = fma4(w2, v2, acc); acc = fma4(w3, v3, acc);
    }
    for (; j < end; ++j) {
        int s0 = ssrc[j];
        float w0 = edge_w(as_[s0 * NH + hd] + adv);
        float4 v0 = *(const float4*)(x + s0 * NF + q * 4);
        wsum += w0;
        acc = fma4(w0, v0, acc);
    }
    float inv = 1.f / wsum;
    acc.x *= inv; acc.y *= inv; acc.z *= inv; acc.w *= inv;
    ((float4*)(aggx1 + (size_t)wv * 256))[lane] = acc;   // [hd*32 + q*4] == lane*4
}

// ---------------- tiled GEMM: Y[nrows,N] = act(A[nrows,K] @ W[K,N] + bias) -------------
// 64x64 tile, K-chunked (KC<=256) transposed-A in LDS, 4x4 register blocking.
// grid = (ceil(nrows/64), N/64), 256 threads.

template<int K, int N, bool RELU>
__global__ __launch_bounds__(256) void tgemm_k(
        const float* __restrict__ A, const float* __restrict__ W,
        const float* __restrict__ bias, float* __restrict__ Y, int nrows) {
    constexpr int KC = (K < 256) ? K : 256;
    __shared__ float As[KC][64];
    int t = threadIdx.x;
    int row0 = blockIdx.x * 64;
    int col0 = blockIdx.y * 64;
    int rr = t & 63;                 // staging row
    int kb = (t >> 6) * (KC / 4);    // staging k-span base
    int r0 = (t >> 4) * 4;           // compute rows
    int c0 = (t & 15) * 4;           // compute cols
    float acc[4][4];
    #pragma unroll
    for (int i = 0; i < 4; ++i)
        #pragma unroll
        for (int j = 0; j < 4; ++j) acc[i][j] = 0.f;

    for (int kc = 0; kc < K; kc += KC) {
        if (kc) __syncthreads();
        {
            int grow = row0 + rr;
            const float* ap = A + (size_t)grow * K + kc + kb;
            #pragma unroll
            for (int i = 0; i < KC / 4; i += 4) {
                float4 v = {0.f, 0.f, 0.f, 0.f};
                if (grow < nrows) v = *(const float4*)(ap + i);
                As[kb + i + 0][rr] = v.x;
                As[kb + i + 1][rr] = v.y;
                As[kb + i + 2][rr] = v.z;
                As[kb + i + 3][rr] = v.w;
            }
        }
        __syncthreads();
        const float* wp = W + (size_t)kc * N + col0 + c0;
        #pragma unroll 4
        for (int k = 0; k < KC; ++k) {
            float4 a = *(const float4*)&As[k][r0];
            float4 w = *(const float4*)(wp + (size_t)k * N);
            acc[0][0] = fmaf(a.x, w.x, acc[0][0]); acc[0][1] = fmaf(a.x, w.y, acc[0][1]);
            acc[0][2] = fmaf(a.x, w.z, acc[0][2]); acc[0][3] = fmaf(a.x, w.w, acc[0][3]);
            acc[1][0] = fmaf(a.y, w.x, acc[1][0]); acc[1][1] = fmaf(a.y, w.y, acc[1][1]);
            acc[1][2] = fmaf(a.y, w.z, acc[1][2]); acc[1][3] = fmaf(a.y, w.w, acc[1][3]);
            acc[2][0] = fmaf(a.z, w.x, acc[2][0]); acc[2][1] = fmaf(a.z, w.y, acc[2][1]);
            acc[2][2] = fmaf(a.z, w.z, acc[2][2]); acc[2][3] = fmaf(a.z, w.w, acc[2][3]);
            acc[3][0] = fmaf(a.w, w.x, acc[3][0]); acc[3][1] = fmaf(a.w, w.y, acc[3][1]);
            acc[3][2] = fmaf(a.w, w.z, acc[3][2]); acc[3][3] = fmaf(a.w, w.w, acc[3][3]);
        }
    }
    float4 bv = *(const float4*)(bias + col0 + c0);
    #pragma unroll
    for (int i = 0; i < 4; ++i) {
        int row = row0 + r0 + i;
        if (row < nrows) {
            float4 o;
            o.x = acc[i][0] + bv.x; o.y = acc[i][1] + bv.y;
            o.z = acc[i][2] + bv.z; o.w = acc[i][3] + bv.w;
            if (RELU) {
                o.x = fmaxf(o.x, 0.f); o.y = fmaxf(o.y, 0.f);
                o.z = fmaxf(o.z, 0.f); o.w = fmaxf(o.w, 0.f);
            }
            *(float4*)&Y[(size_t)row * N + col0 + c0] = o;
        }
    }
}

// ---------------- layer-2 aggregation + pooling: ONE BLOCK PER GRAPH, zero atomics ----------

__global__ __launch_bounds__(256) void agg2g_k(
        const float* __restrict__ hx, const float* __restrict__ as_,
        const float* __restrict__ ad_, const int* __restrict__ ssrc,
        const int* __restrict__ off, const int* __restrict__ cnt,
        const int* __restrict__ goff, float* __restrict__ P) {
    int g = blockIdx.x;
    int w = threadIdx.x >> 6;
    int lane = threadIdx.x & 63;
    int hd = lane >> 3, q = lane & 7;
    int nbeg = goff[g], nend = goff[g + 1];

    __shared__ float sp[4][512];

    float4 p0 = {0.f, 0.f, 0.f, 0.f}, p1 = {0.f, 0.f, 0.f, 0.f};

    for (int nd0 = nbeg + w; nd0 < nend; nd0 += 4) {
        int nd = __builtin_amdgcn_readfirstlane(nd0);
        int beg = off[nd], end = beg + cnt[nd];
        float adv = ad_[nd * NH + hd];

        float4 a0 = {0.f, 0.f, 0.f, 0.f}, a1 = {0.f, 0.f, 0.f, 0.f};
        float wsum = 0.f;
        int j = beg;
        for (; j + 4 <= end; j += 4) {
            int s0 = ssrc[j], s1 = ssrc[j + 1], s2 = ssrc[j + 2], s3 = ssrc[j + 3];
            float e0 = as_[s0 * NH + hd], e1 = as_[s1 * NH + hd];
            float e2 = as_[s2 * NH + hd], e3 = as_[s3 * NH + hd];
            const float4* pp0 = (const float4*)(hx + s0 * DE + q * 8);
            const float4* pp1 = (const float4*)(hx + s1 * DE + q * 8);
            const float4* pp2 = (const float4*)(hx + s2 * DE + q * 8);
            const float4* pp3 = (const float4*)(hx + s3 * DE + q * 8);
            float4 v00 = pp0[0], v01 = pp0[1];
            float4 v10 = pp1[0], v11 = pp1[1];
            float4 v20 = pp2[0], v21 = pp2[1];
            float4 v30 = pp3[0], v31 = pp3[1];
            float w0 = edge_w(e0 + adv), w1 = edge_w(e1 + adv);
            float w2 = edge_w(e2 + adv), w3 = edge_w(e3 + adv);
            wsum += (w0 + w1) + (w2 + w3);
            a0 = fma4(w0, v00, a0); a1 = fma4(w0, v01, a1);
            a0 = fma4(w1, v10, a0); a1 = fma4(w1, v11, a1);
            a0 = fma4(w2, v20, a0); a1 = fma4(w2, v21, a1);
            a0 = fma4(w3, v30, a0); a1 = fma4(w3, v31, a1);
        }
        for (; j < end; ++j) {
            int s0 = ssrc[j];
            float w0 = edge_w(as_[s0 * NH + hd] + adv);
            const float4* pp0 = (const float4*)(hx + s0 * DE + q * 8);
            float4 v00 = pp0[0], v01 = pp0[1];
            wsum += w0;
            a0 = fma4(w0, v00, a0); a1 = fma4(w0, v01, a1);
        }
        float inv = 1.f / wsum;
        p0 = fma4(inv, a0, p0);
        p1 = fma4(inv, a1, p1);
    }

    ((float4*)&sp[w][lane * 8])[0] = p0;
    ((float4*)&sp[w][lane * 8 + 4])[0] = p1;
    __syncthreads();
    int t = threadIdx.x;
    float s0 = sp[0][t] + sp[1][t] + sp[2][t] + sp[3][t];
    float s1 = sp[0][t + 256] + sp[1][t + 256] + sp[2][t + 256] + sp[3][t + 256];
    P[(size_t)g * CT + t]       = s0;
    P[(size_t)g * CT + t + 256] = s1;
}

// ---------------- layer-2 projection on POOLED tensor (block-diagonal per head) ----------

__global__ void proj2_k(const float* __restrict__ P, const float* __restrict__ W2,
                        const float* __restrict__ b2, const int* __restrict__ goff,
                        float* __restrict__ g0) {
    int gid = blockIdx.x * 256 + threadIdx.x;
    if (gid >= NG * CT) return;
    int b = gid >> 9, ch = gid & 511;
    int hd = ch >> 6, f = ch & 63;
    const float* Pp = P + (size_t)b * CT + hd * 64;
    int cnt = goff[b + 1] - goff[b];
    float acc = (float)cnt * b2[ch];
    #pragma unroll 4
    for (int c = 0; c < 64; ++c)
        acc = fmaf(Pp[c], W2[c * 512 + hd * 64 + f], acc);
    g0[gid] = acc;
}

__global__ void mlp_out_k(const float* __restrict__ gin, const float* __restrict__ w,
                          const float* __restrict__ b, float* __restrict__ out) {
    int row = blockIdx.x * 4 + (threadIdx.x >> 6);
    int lane = threadIdx.x & 63;
    if (row >= NG) return;
    float s = 0.f;
    for (int k = lane; k < DMLP; k += 64) s += gin[(size_t)row * DMLP + k] * w[k];
    #pragma unroll
    for (int d = 32; d >= 1; d >>= 1) s += __shfl_xor(s, d, 64);
    if (lane == 0) out[row] = s + b[0];
}

// ---------------- launch ----------------

extern "C" void kernel_launch(void* const* d_in, const int* in_sizes, int n_in,
                              void* d_out, int out_size, void* d_ws, size_t ws_size,
                              hipStream_t stream) {
    const float* x     = (const float*)d_in[0];
    const int*   ei    = (const int*)d_in[1];
    const int*   batch = (const int*)d_in[2];
    const float* W1    = (const float*)d_in[3];
    const float* asrc1 = (const float*)d_in[4];
    const float* adst1 = (const float*)d_in[5];
    const float* b1    = (const float*)d_in[6];
    const float* W2    = (const float*)d_in[7];
    const float* asrc2 = (const float*)d_in[8];
    const float* adst2 = (const float*)d_in[9];
    const float* b2    = (const float*)d_in[10];
    const float* fcW1  = (const float*)d_in[11];
    const float* fcb1  = (const float*)d_in[12];
    const float* fcW2  = (const float*)d_in[13];
    const float* fcb2  = (const float*)d_in[14];
    const float* fcW3  = (const float*)d_in[15];
    const float* fcb3  = (const float*)d_in[16];

    char* p = (char*)d_ws;
    auto take = [&](size_t bytes) {
        char* r = p;
        p += (bytes + 255) & ~(size_t)255;
        return r;
    };
    float* aggx1 = (float*)take((size_t)N_NODES * 256 * 4);  // 51.2 MB
    float* hx    = (float*)take((size_t)N_NODES * DE * 4);   // 12.8 MB
    float* as_   = (float*)take((size_t)N_NODES * NH * 4);
    float* ad_   = (float*)take((size_t)N_NODES * NH * 4);
    int*   ssrc  = (int*)take((size_t)(N_EDGES + N_NODES) * 4);
    int*   offv  = (int*)take((size_t)N_NODES * 4);
    int*   cntv  = (int*)take((size_t)N_NODES * 4);
    int*   cur   = (int*)take((size_t)N_NODES * 4);
    int*   total = (int*)take(256);
    int*   goff  = (int*)take((size_t)(NG + 1) * 4);
    float* B1s   = (float*)take(256 * 4);
    float* B1d   = (float*)take(256 * 4);
    float* B2s   = (float*)take(512 * 4);
    float* B2d   = (float*)take(512 * 4);
    float* U1    = (float*)take(256 * 64 * 4);
    float* P     = (float*)take((size_t)NG * CT * 4);        // pooled per-head agg
    float* g0    = (float*)take((size_t)NG * DMLP * 4);
    float* g1    = (float*)take((size_t)NG * DMLP * 4);
    float* g2    = (float*)take((size_t)NG * DMLP * 4);

    // CSR build (once; reused by both layers) + graph offsets
    init_count_k<<<(N_NODES + 255) / 256, 256, 0, stream>>>(cntv);
    hist_k<<<(N_EDGES + 255) / 256, 256, 0, stream>>>(ei, cntv);
    hipMemsetAsync(total, 0, 4, stream);
    hipMemsetAsync(cur, 0, (size_t)N_NODES * 4, stream);
    alloc_off_k<<<(N_NODES + 255) / 256, 256, 0, stream>>>(cntv, offv, total);
    scatter_k<<<(N_EDGES + N_NODES + 255) / 256, 256, 0, stream>>>(ei, offv, cur, ssrc);
    goffs_k<<<(N_NODES + 255) / 256, 256, 0, stream>>>(batch, goff);

    // weight precompute
    prep_k<<<(768 + 256 * 64 + 255) / 256, 256, 0, stream>>>(
        W1, asrc1, adst1, W2, asrc2, adst2, B1s, B1d, B2s, B2d, U1);

    // Layer 1: logits from x, aggregate x per head, tiled-GEMM projection
    alpha_x_k<NF><<<(N_NODES * NH + 255) / 256, 256, 0, stream>>>(x, B1s, B1d, as_, ad_);
    agg1_k<<<(N_NODES + 3) / 4, 256, 0, stream>>>(x, as_, ad_, ssrc, offv, cntv, aggx1);
    {
        dim3 grid((N_NODES + 63) / 64, 1);
        tgemm_k<256, 64, false><<<grid, 256, 0, stream>>>(aggx1, U1, b1, hx, N_NODES);
    }

    // Layer 2: logits from hx, block-per-graph aggregate+pool, project pooled
    alpha_x_k<DE><<<(N_NODES * NH + 255) / 256, 256, 0, stream>>>(hx, B2s, B2d, as_, ad_);
    agg2g_k<<<NG, 256, 0, stream>>>(hx, as_, ad_, ssrc, offv, cntv, goff, P);
    proj2_k<<<(NG * CT + 255) / 256, 256, 0, stream>>>(P, W2, b2, goff, g0);

    // MLP head
    {
        dim3 grid((NG + 63) / 64, DMLP / 64);
        tgemm_k<DMLP, DMLP, true><<<grid, 256, 0, stream>>>(g0, fcW1, fcb1, g1, NG);
        tgemm_k<DMLP, DMLP, true><<<grid, 256, 0, stream>>>(g1, fcW2, fcb2, g2, NG);
    }
    mlp_out_k<<<(NG + 3) / 4, 256, 0, stream>>>(g2, fcW3, fcb3, (float*)d_out);
}